// Round 1
// baseline (81.099 us; speedup 1.0000x reference)
//
#include <hip/hip_runtime.h>

#define NMAX 64
#define MPB 4   // molecules (one wave each) per 256-thread block

// One wave per molecule, MPB waves per block. Lane t = atom t.
// Offsets derived in-kernel via block-cooperative prefix sum of num_atoms
// (16 KB table, L1/L2-hot). Final penalty sum fused here: one atomicAdd
// per block into out[0] (zeroed by a 4-byte memset) -> no workspace, no
// second kernel.
__global__ __launch_bounds__(256) void mol_kernel(
    const float* __restrict__ coords,      // [N,3] flat
    const int*   __restrict__ species,     // [N]
    const int*   __restrict__ num_atoms,   // [B]
    const float* __restrict__ radii,       // [95]
    float* __restrict__ out,               // [1 + 3N]
    int Bm, float invB) {
    const int w      = threadIdx.x >> 6;
    const int tw     = threadIdx.x & 63;
    const int t      = threadIdx.x;
    const int base_m = blockIdx.x * MPB;
    const int m      = base_m + w;

    __shared__ float4 s4[MPB][NMAX];   // {x,y,z,r} per atom, wave-private slice
    __shared__ int    ssum[MPB];
    __shared__ float  spen[MPB];

    // Block-cooperative exclusive prefix: sum num_atoms[0..base_m).
    // <=17 coalesced strided loads per thread (table is hot in L1/L2).
    int acc = 0;
    for (int i = t; i < base_m; i += 256) acc += num_atoms[i];
    #pragma unroll
    for (int d = 32; d > 0; d >>= 1) acc += __shfl_down(acc, d);
    if (tw == 0) ssum[w] = acc;
    __syncthreads();                   // all waves reach this (no early return)
    const int block_base = ssum[0] + ssum[1] + ssum[2] + ssum[3];

    // NOTE: no early return anywhere — every thread reaches the final
    // __syncthreads (Bm%MPB==0 for this problem, but stay robust).
    const bool mvalid = (m < Bm);
    const int  n      = mvalid ? num_atoms[m] : 0;
    const int  mm     = mvalid ? m : Bm;
    int off = block_base;
    for (int i = base_m; i < mm; ++i) off += num_atoms[i];  // <=3 uniform loads

    // Per-lane direct load: lane t owns atom t (wave covers 768 contiguous B).
    float x = 0.f, y = 0.f, z = 0.f, r = 0.f;
    const bool act = (tw < n);
    if (act) {
        const float* cp = coords + 3 * (size_t)(off + tw);
        x = cp[0]; y = cp[1]; z = cp[2];
        r = radii[species[off + tw]];
    }
    s4[w][tw] = make_float4(x, y, z, r);   // wave-private: no barrier needed

    // Segment mean via wave reduce (inactive lanes contribute 0).
    float sx = x, sy = y, sz = z;
    #pragma unroll
    for (int d = 32; d > 0; d >>= 1) {
        sx += __shfl_down(sx, d);
        sy += __shfl_down(sy, d);
        sz += __shfl_down(sz, d);
    }
    const float invn = (n > 0) ? 1.0f / (float)n : 0.0f;
    const float mx = __shfl(sx, 0) * invn;
    const float my = __shfl(sy, 0) * invn;
    const float mz = __shfl(sz, 0) * invn;

    // Pairwise repulsion: one broadcast ds_read_b128 per j (pipelined 4-deep).
    // Math kept bit-identical to the verified version (absmax margin).
    float pen = 0.0f;
    if (act) {
        #pragma unroll 4
        for (int j = 0; j < n; ++j) {
            float4 aj = s4[w][j];
            float dx = x - aj.x;
            float dy = y - aj.y;
            float dz = z - aj.z;
            float dist = sqrtf(dx * dx + dy * dy + dz * dz + 1e-8f);
            float v = (r + aj.w) * 0.8f - dist;
            pen += (j != tw && v > 0.0f) ? v * v : 0.0f;
        }
    }
    #pragma unroll
    for (int d = 32; d > 0; d >>= 1) pen += __shfl_down(pen, d);
    if (tw == 0) spen[w] = (n > 1) ? pen * invn : 0.0f;

    // Centered write straight from registers (contiguous 768 B/wave region).
    if (act) {
        float* op = out + 1 + 3 * (size_t)(off + tw);
        op[0] = x - mx;
        op[1] = y - my;
        op[2] = z - mz;
    }

    // Fused final reduction: one device-scope atomic per block (1026 total,
    // staggered by block completion — no meaningful contention).
    __syncthreads();
    if (t == 0) {
        float s = spen[0] + spen[1] + spen[2] + spen[3];
        atomicAdd(out, s * invB);
    }
}

extern "C" void kernel_launch(void* const* d_in, const int* in_sizes, int n_in,
                              void* d_out, int out_size, void* d_ws, size_t ws_size,
                              hipStream_t stream) {
    const float* cart_coords = (const float*)d_in[0];
    const int*   species     = (const int*)d_in[1];
    // d_in[2] = batch_indices (unused: offsets derived from num_atoms in-kernel)
    const int*   num_atoms   = (const int*)d_in[3];
    const float* radii_table = (const float*)d_in[4];

    const int Bm = in_sizes[3];       // num_atoms is [B]
    float* out = (float*)d_out;

    // Zero the l_repulsion accumulator (graph-capturable memset node).
    hipMemsetAsync(out, 0, sizeof(float), stream);

    mol_kernel<<<(Bm + MPB - 1) / MPB, 256, 0, stream>>>(
        cart_coords, species, num_atoms, radii_table, out, Bm,
        1.0f / (float)Bm);
}